// Round 5
// baseline (40.284 us; speedup 1.0000x reference)
//
#include <hip/hip_runtime.h>
#include <hip/hip_bf16.h>
#include <cstdint>
#include <cstddef>

// Problem constants (from reference)
#define NN     50000   // nodes
#define FIN    128
#define FOUT   128
#define FLIN   64
#define BM     32      // rows per tile
#define NT     1563    // ceil(NN/BM)
#define GRID   512     // persistent blocks, 2 per CU

typedef __attribute__((ext_vector_type(4))) float f32x4;
typedef __attribute__((ext_vector_type(8))) short s16x8;

// Saturating-limit fast sigmoid/tanh: NaN-free at +/-inf.
__device__ __forceinline__ float fsigmoid(float x) {
    return __builtin_amdgcn_rcpf(1.f + __builtin_amdgcn_exp2f(-1.4426950408889634f * x));
}
__device__ __forceinline__ float ftanh(float x) {
    return 1.f - 2.f * __builtin_amdgcn_rcpf(1.f + __builtin_amdgcn_exp2f(2.8853900817779268f * x));
}

// Pack 8 floats -> bf16 fragment via v_cvt_pk_bf16_f32 (RNE).
__device__ __forceinline__ s16x8 pack_frag8(f32x4 a, f32x4 b) {
    union { unsigned int u[4]; s16x8 v; } r;
    __hip_bfloat162 p0 = __float22bfloat162_rn(make_float2(a.x, a.y));
    __hip_bfloat162 p1 = __float22bfloat162_rn(make_float2(a.z, a.w));
    __hip_bfloat162 p2 = __float22bfloat162_rn(make_float2(b.x, b.y));
    __hip_bfloat162 p3 = __float22bfloat162_rn(make_float2(b.z, b.w));
    r.u[0] = *(unsigned int*)&p0;
    r.u[1] = *(unsigned int*)&p1;
    r.u[2] = *(unsigned int*)&p2;
    r.u[3] = *(unsigned int*)&p3;
    return r.v;
}

// Gather one B fragment (16x16x32 bf16) from row-major (K x ncols) f32:
// lane holds W[kb*32 + lg*8 + i][ct*16 + lc], i = 0..7.
__device__ __forceinline__ s16x8 gather_bfrag(const float* __restrict__ W,
                                              int ncols, int kb, int ct,
                                              int lg, int lc) {
    const float* p = W + (size_t)(kb * 32 + lg * 8) * ncols + ct * 16 + lc;
    float f[8];
    #pragma unroll
    for (int i = 0; i < 8; ++i) f[i] = p[(size_t)i * ncols];
    f32x4 a = {f[0], f[1], f[2], f[3]};
    f32x4 b = {f[4], f[5], f[6], f[7]};
    return pack_frag8(a, b);
}

// ---------------------------------------------------------------------------
// Persistent fused kernel v5: 512 blocks x 512 threads (8 waves). Each wave
// owns ONE 16-col tile (ct = wave id) of every gate. Gate i,c B-frags live in
// registers (32 VGPR); gate o frags + lin_W frags live in LDS. A-fragments
// are gathered straight from global x (L1-resident tile; no LDS staging, no
// prefetch regs). One barrier per tile via double-buffered h.
// ---------------------------------------------------------------------------
__global__ __launch_bounds__(512, 4) void gclstm_fused(
    const float* __restrict__ x,
    const float* __restrict__ Wx,               // (4,128,128)
    const float* __restrict__ b_gate,           // (4,1,128)
    const float* __restrict__ w_c,              // (3,1,128)
    const float* __restrict__ cheb_b,           // (4,128)
    const float* __restrict__ lin_W,            // (128,64)
    const float* __restrict__ lin_b,            // (64)
    float* __restrict__ out)                    // (NN,64)
{
    __shared__ __align__(16) unsigned char ldsh[2][BM * 256];   // 2 x 8KB swizzled h
    __shared__ __align__(16) unsigned char ldso[8 * 4 * 1024];  // 32KB o-gate frags
    __shared__ __align__(16) unsigned char ldsw[16 * 1024];     // 16KB lin frags

    const int tid  = threadIdx.x;
    const int w    = tid >> 6;       // wave 0..7 = col tile (phase 1)
    const int lane = tid & 63;
    const int lg   = lane >> 4;      // 0..3
    const int lc   = lane & 15;

    // ---- prologue: persistent weights ----
    // gates i = Wx[0], c = Wx[2] -> registers; o = Wx[3] -> LDS
    s16x8 bfr[2][4];
    #pragma unroll
    for (int kb = 0; kb < 4; ++kb) {
        bfr[0][kb] = gather_bfrag(Wx + 0 * (FIN * FOUT), FOUT, kb, w, lg, lc);
        bfr[1][kb] = gather_bfrag(Wx + 2 * (FIN * FOUT), FOUT, kb, w, lg, lc);
        s16x8 of = gather_bfrag(Wx + 3 * (FIN * FOUT), FOUT, kb, w, lg, lc);
        *(s16x8*)(ldso + ((size_t)(w * 4 + kb) * 64 + lane) * 16) = of;   // own-wave read only
    }
    #pragma unroll
    for (int it = 0; it < 2; ++it) {
        int fi = w * 2 + it;          // 0..15: ct = fi>>2, kb = fi&3
        s16x8 f = gather_bfrag(lin_W, FLIN, fi & 3, fi >> 2, lg, lc);
        *(s16x8*)(ldsw + ((size_t)fi * 64 + lane) * 16) = f;
    }

    // ---- biases ----
    const int col1 = w * 16 + lc;               // phase-1 col
    const float bi  = cheb_b[0 * 128 + col1] + b_gate[0 * 128 + col1];
    const float bc  = cheb_b[2 * 128 + col1] + b_gate[2 * 128 + col1];
    const float bo  = cheb_b[3 * 128 + col1] + b_gate[3 * 128 + col1];
    const float wco = w_c[2 * 128 + col1];
    const int rt2 = w & 1;                      // phase-2 row tile
    const int ctL = w >> 1;                     // phase-2 col tile
    const int colL = ctL * 16 + lc;
    const float lb = lin_b[colL];

    int buf = 0;
    for (int t = blockIdx.x; t < NT; t += GRID) {
        const long m0 = (long)t * BM;

        // ---- phase 1: acc[rt][gg], A-frags direct from global ----
        f32x4 acc[2][3];
        #pragma unroll
        for (int rt = 0; rt < 2; ++rt)
            #pragma unroll
            for (int gg = 0; gg < 3; ++gg)
                acc[rt][gg] = (f32x4){0.f, 0.f, 0.f, 0.f};

        #pragma unroll
        for (int rt = 0; rt < 2; ++rt) {
            const long row = m0 + rt * 16 + lc;
            const bool ok = (row < NN);
            const float* rp = x + row * FIN + lg * 8;
            #pragma unroll
            for (int kb = 0; kb < 4; ++kb) {
                f32x4 a0 = {0.f, 0.f, 0.f, 0.f}, a1 = {0.f, 0.f, 0.f, 0.f};
                if (ok) {
                    a0 = *(const f32x4*)(rp + kb * 32);
                    a1 = *(const f32x4*)(rp + kb * 32 + 4);
                }
                s16x8 afr = pack_frag8(a0, a1);
                s16x8 of  = *(const s16x8*)(ldso + ((size_t)(w * 4 + kb) * 64 + lane) * 16);
                acc[rt][0] = __builtin_amdgcn_mfma_f32_16x16x32_bf16(afr, bfr[0][kb], acc[rt][0], 0, 0, 0);
                acc[rt][1] = __builtin_amdgcn_mfma_f32_16x16x32_bf16(afr, bfr[1][kb], acc[rt][1], 0, 0, 0);
                acc[rt][2] = __builtin_amdgcn_mfma_f32_16x16x32_bf16(afr, of,         acc[rt][2], 0, 0, 0);
            }
        }

        // ---- epilogue: LSTM cell (H=C=0), h -> ldsh[buf] ----
        #pragma unroll
        for (int rt = 0; rt < 2; ++rt)
            #pragma unroll
            for (int r = 0; r < 4; ++r) {
                float I = fsigmoid(acc[rt][0][r] + bi);
                float T = ftanh(acc[rt][1][r] + bc);
                float C = I * T;
                float O = fsigmoid(acc[rt][2][r] + wco * C + bo);
                float h = fmaxf(O * ftanh(C), 0.f);
                int row  = rt * 16 + lg * 4 + r;
                int byte = (row * 256 + col1 * 2) ^ ((row & 7) << 4);
                *(unsigned short*)(ldsh[buf] + byte) = __bfloat16_as_ushort(__float2bfloat16(h));
            }
        __syncthreads();

        // ---- phase 2: out = h @ lin_W + lin_b ----
        f32x4 acc2 = {0.f, 0.f, 0.f, 0.f};
        #pragma unroll
        for (int kb = 0; kb < 4; ++kb) {
            int row  = rt2 * 16 + lc;
            int byte = (row * 256 + kb * 64 + lg * 16) ^ ((row & 7) << 4);
            s16x8 ha = *(const s16x8*)(ldsh[buf] + byte);
            s16x8 lf = *(const s16x8*)(ldsw + ((size_t)(ctL * 4 + kb) * 64 + lane) * 16);
            acc2 = __builtin_amdgcn_mfma_f32_16x16x32_bf16(ha, lf, acc2, 0, 0, 0);
        }
        #pragma unroll
        for (int r = 0; r < 4; ++r) {
            long row = m0 + rt2 * 16 + lg * 4 + r;
            if (row < NN) out[row * FLIN + colL] = acc2[r] + lb;
        }

        buf ^= 1;
    }
}

extern "C" void kernel_launch(void* const* d_in, const int* in_sizes, int n_in,
                              void* d_out, int out_size, void* d_ws, size_t ws_size,
                              hipStream_t stream) {
    const float* x      = (const float*)d_in[0];
    // d_in[1] edge_index, d_in[2] edge_weight, d_in[6] cheb_W: dead (H=C=0)
    const float* Wx     = (const float*)d_in[3];
    const float* b_gate = (const float*)d_in[4];
    const float* w_c    = (const float*)d_in[5];
    const float* cheb_b = (const float*)d_in[7];
    const float* lin_W  = (const float*)d_in[8];
    const float* lin_b  = (const float*)d_in[9];
    float* out          = (float*)d_out;

    gclstm_fused<<<GRID, 512, 0, stream>>>(x, Wx, b_gate, w_c, cheb_b, lin_W, lin_b, out);
}